// Round 6
// baseline (68.131 us; speedup 1.0000x reference)
//
#include <hip/hip_runtime.h>
#include <hip/hip_bf16.h>
#include <stdint.h>

typedef float f32x4 __attribute__((ext_vector_type(4)));
typedef short s16x8 __attribute__((ext_vector_type(8)));
typedef unsigned short u16;
typedef u16 u16x4 __attribute__((ext_vector_type(4)));

__device__ __forceinline__ u16 f2bf(float f) {
    union { __hip_bfloat16 h; u16 u; } cv;
    cv.h = __float2bfloat16(f);
    return cv.u;
}
__device__ __forceinline__ int pkbf(float lo, float hi) {
    return (int)(unsigned)f2bf(lo) | ((int)(unsigned)f2bf(hi) << 16);
}
__device__ __forceinline__ f32x4 mfma16(s16x8 a, s16x8 b, f32x4 c) {
    return __builtin_amdgcn_mfma_f32_16x16x32_bf16(a, b, c, 0, 0, 0);
}
__device__ __forceinline__ float exp2_hw(float x) {
    float r; asm("v_exp_f32 %0, %1" : "=v"(r) : "v"(x)); return r;
}
// lane ^= 16 within 32-lane halves (verified R4/R5)
__device__ __forceinline__ int swz16(int v) {
    return __builtin_amdgcn_ds_swizzle(v, 0x401F);
}
// value at lane^32 (verified R4/R5)
__device__ __forceinline__ int xor32i(int v, bool lo32) {
    auto r = __builtin_amdgcn_permlane32_swap(v, v, false, false);
    return lo32 ? r[1] : r[0];
}
// lanes>=32 receive (lane-32)'s value; lanes<32 keep own (verified R5)
__device__ __forceinline__ int pl_lo_to_hi(int v) {
    auto r = __builtin_amdgcn_permlane32_swap(v, v, false, false);
    return r[0];
}
__device__ __forceinline__ s16x8 frag4(int d0, int d1, int d2, int d3) {
    union { int i[4]; s16x8 v; } u;
    u.i[0] = d0; u.i[1] = d1; u.i[2] = d2; u.i[3] = d3;
    return u.v;
}

// x: (4,512,512,32) f32. Window=4, shift=2, heads=4, d=8.
// 1 wave = 1 window (16 tokens), 4 independent waves/block, 8 windows/wave.
// Double-buffered LDS staging, register P (permlane/swizzle), no fences.
__global__ __launch_bounds__(256) void swin_attn_kernel(
    const float* __restrict__ x,
    const float* __restrict__ Wq, const float* __restrict__ bq,
    const float* __restrict__ Wk, const float* __restrict__ bk,
    const float* __restrict__ Wv, const float* __restrict__ bv,
    const float* __restrict__ Wo, const float* __restrict__ bo,
    float* __restrict__ out)
{
    const int lane  = threadIdx.x & 63;
    const int wave  = threadIdx.x >> 6;
    const int c16   = lane & 15;
    const int g     = lane >> 4;
    const bool lo32 = (lane < 32);

    // 30.7 KB/block -> 5 blocks/CU (20 waves)
    __shared__ __align__(16) u16 qk_bf[2][4][16][72]; // [buf][wave][token][q0..31,k32..63]
    __shared__ __align__(16) u16 vT_bf[2][4][32][24]; // [buf][wave][vslot(hd)][token]

    const float qscale = 0.35355339059327373f * 1.4426950408889634f; // 1/sqrt(8)*log2e

    // ---- weights in registers (layouts proven R5) ----
    s16x8 wqkv[6];
    #pragma unroll
    for (int j = 0; j < 6; ++j) {
        const float* Wsrc = (j < 2) ? Wq : (j < 4) ? Wk : Wv;
        const int colW = ((j & 1) << 4) | c16;
        const float sc = (j < 2) ? qscale : 1.0f;
        s16x8 wf;
        #pragma unroll
        for (int jj = 0; jj < 8; ++jj)
            wf[jj] = (short)f2bf(Wsrc[(g * 8 + jj) * 32 + colW] * sc);
        wqkv[j] = wf;
    }
    f32x4 bias_qk[4];
    #pragma unroll
    for (int j = 0; j < 4; ++j) {
        const float* bsrc = (j < 2) ? bq : bk;
        const float sc = (j < 2) ? qscale : 1.0f;
        #pragma unroll
        for (int i = 0; i < 4; ++i)
            bias_qk[j][i] = bsrc[((j & 1) << 4) + 4 * g + i] * sc;
    }
    f32x4 bias_v[2];
    #pragma unroll
    for (int jv = 0; jv < 2; ++jv) {
        float b = bv[jv * 16 + c16];
        bias_v[jv] = (f32x4){b, b, b, b};
    }
    s16x8 wo_frag[2];
    f32x4 bo_frag[2];
    #pragma unroll
    for (int j2 = 0; j2 < 2; ++j2) {
        const int cout = j2 * 16 + c16;
        s16x8 wf;
        #pragma unroll
        for (int jj = 0; jj < 8; ++jj) {
            const int h = (g >> 1) * 2 + (jj >> 2);
            const int d = 4 * (g & 1) + (jj & 3);
            wf[jj] = (short)f2bf(Wo[(h * 8 + d) * 32 + cout]);
        }
        wo_frag[j2] = wf;
        #pragma unroll
        for (int i = 0; i < 4; ++i)
            bo_frag[j2][i] = bo[j2 * 16 + 4 * g + i];
    }

    const f32x4 zero4 = {0.f, 0.f, 0.f, 0.f};
    const s16x8 zero8 = {0, 0, 0, 0, 0, 0, 0, 0};

    // prologue: load window 0's x
    const int wbase = (blockIdx.x * 4 + wave) * 8;
    long curpix;
    f32x4 px0, px1;
    {
        const int w = wbase;
        const int b = w >> 14, rem = w & 16383, wi = rem >> 7, wj = rem & 127;
        const int row  = (wi * 4 + (c16 >> 2) + 2) & 511;
        const int colp = (wj * 4 + (c16 & 3) + 2) & 511;
        curpix = ((((long)b << 9) + row) * 512 + colp) * 32;
        px0 = *(const f32x4*)(x + curpix + g * 8);
        px1 = *(const f32x4*)(x + curpix + g * 8 + 4);
    }

    #pragma unroll 2
    for (int it = 0; it < 8; ++it) {
        const int pb = it & 1; // constant per unrolled copy
        const long pixbase = curpix;
        s16x8 xfrag = frag4(pkbf(px0[0], px0[1]), pkbf(px0[2], px0[3]),
                            pkbf(px1[0], px1[1]), pkbf(px1[2], px1[3]));

        // ---- phase A: projections -> LDS staging (buffer pb) ----
        #pragma unroll
        for (int j = 0; j < 4; ++j) {     // q,k: C^T = W^T X^T (token-major)
            f32x4 c = mfma16(wqkv[j], xfrag, bias_qk[j]);
            u16x4 qv;
            #pragma unroll
            for (int i = 0; i < 4; ++i) qv[i] = f2bf(c[i]);
            *(u16x4*)&qk_bf[pb][wave][c16][j * 16 + 4 * g] = qv;
        }
        #pragma unroll
        for (int jv = 0; jv < 2; ++jv) {  // v: C = X Wv (vslot-major)
            f32x4 c = mfma16(xfrag, wqkv[4 + jv], bias_v[jv]);
            u16x4 vv;
            #pragma unroll
            for (int i = 0; i < 4; ++i) vv[i] = f2bf(c[i]);
            *(u16x4*)&vT_bf[pb][wave][jv * 16 + c16][4 * g] = vv;
        }

        // prefetch next window's x (wrap at it==7: harmless re-read)
        {
            const int w = wbase + ((it + 1) & 7);
            const int b = w >> 14, rem = w & 16383, wi = rem >> 7, wj = rem & 127;
            const int row  = (wi * 4 + (c16 >> 2) + 2) & 511;
            const int colp = (wj * 4 + (c16 & 3) + 2) & 511;
            const long np = ((((long)b << 9) + row) * 512 + colp) * 32;
            px0 = *(const f32x4*)(x + np + g * 8);
            px1 = *(const f32x4*)(x + np + g * 8 + 4);
            curpix = np;
        }
        f32x4 r0 = *(const f32x4*)(x + pixbase + 4 * g);
        f32x4 r1 = *(const f32x4*)(x + pixbase + 16 + 4 * g);

        // ---- phase B: per head, scores + softmax + register-P + PV ----
        f32x4 o_acc[4];
        #pragma unroll
        for (int h = 0; h < 4; ++h) {
            s16x8 afrag = zero8, bfrag = zero8;
            if (g == 0) { // k=d<8 only
                afrag = *(const s16x8*)&qk_bf[pb][wave][c16][32 + h * 8]; // K_h[kt=c16][d]
                bfrag = *(const s16x8*)&qk_bf[pb][wave][c16][h * 8];      // Q_h[qt=c16][d]
            }
            f32x4 s = mfma16(afrag, bfrag, zero4); // S^T rows kt=4g+i, col qt=c16

            float e0 = exp2_hw(s[0]), e1 = exp2_hw(s[1]);
            float e2 = exp2_hw(s[2]), e3 = exp2_hw(s[3]);
            float part = (e0 + e1) + (e2 + e3);
            float sum  = part + __int_as_float(swz16(__float_as_int(part)));
            sum += __int_as_float(xor32i(__float_as_int(sum), lo32));
            const float inv = __builtin_amdgcn_rcpf(sum);

            // P pack: lane holds P[kt=4g+i][qt=c16] -> build B-frag in registers.
            // pfrag lane (c16,g): jj-th elem = P[kt=g*8+jj][qt=c16], g<2; else 0.
            int dwA = pkbf(e0 * inv, e1 * inv);   // kt 4g, 4g+1
            int dwB = pkbf(e2 * inv, e3 * inv);   // kt 4g+2, 4g+3
            int sA = swz16(dwA), sB = swz16(dwB); // from lane^16
            int tA = xor32i(dwA, lo32), tB = xor32i(dwB, lo32); // from lane^32
            int uA = xor32i(sA, lo32),  uB = xor32i(sB, lo32);  // from lane^48
            const bool g0 = (g == 0), g1 = (g == 1);
            s16x8 pfrag = frag4(g0 ? dwA : (g1 ? uA : 0),
                                g0 ? dwB : (g1 ? uB : 0),
                                g0 ? sA  : (g1 ? tA : 0),
                                g0 ? sB  : (g1 ? tB : 0));

            s16x8 vfrag = zero8;
            if (g < 2)
                vfrag = *(const s16x8*)&vT_bf[pb][wave][h * 8 + (c16 & 7)][g * 8];
            o_acc[h] = mfma16(vfrag, pfrag, zero4); // O_h rows d=4g+i (g<2), col qt=c16
        }

        // ---- phase C: ofrag from registers (proven R5) ----
        int t00 = pkbf(o_acc[0][0], o_acc[0][1]), t01 = pkbf(o_acc[0][2], o_acc[0][3]);
        int t10 = pkbf(o_acc[1][0], o_acc[1][1]), t11 = pkbf(o_acc[1][2], o_acc[1][3]);
        int t20 = pkbf(o_acc[2][0], o_acc[2][1]), t21 = pkbf(o_acc[2][2], o_acc[2][3]);
        int t30 = pkbf(o_acc[3][0], o_acc[3][1]), t31 = pkbf(o_acc[3][2], o_acc[3][3]);
        int m20 = pl_lo_to_hi(t20), m21 = pl_lo_to_hi(t21);
        int m30 = pl_lo_to_hi(t30), m31 = pl_lo_to_hi(t31);
        s16x8 ofrag = frag4(lo32 ? t00 : m20, lo32 ? t01 : m21,
                            lo32 ? t10 : m30, lo32 ? t11 : m31);

        // ---- out-proj + bias + residual + store ----
        f32x4 ci0 = bo_frag[0], ci1 = bo_frag[1];
        #pragma unroll
        for (int i = 0; i < 4; ++i) { ci0[i] += r0[i]; ci1[i] += r1[i]; }
        f32x4 c0 = mfma16(wo_frag[0], ofrag, ci0); // rows cout 4g+i, col token c16
        f32x4 c1 = mfma16(wo_frag[1], ofrag, ci1);
        *(f32x4*)(out + pixbase + 4 * g) = c0;
        *(f32x4*)(out + pixbase + 16 + 4 * g) = c1;
    }
}

extern "C" void kernel_launch(void* const* d_in, const int* in_sizes, int n_in,
                              void* d_out, int out_size, void* d_ws, size_t ws_size,
                              hipStream_t stream) {
    const float* x  = (const float*)d_in[0];
    const float* Wq = (const float*)d_in[1];
    const float* bq = (const float*)d_in[2];
    const float* Wk = (const float*)d_in[3];
    const float* bk = (const float*)d_in[4];
    const float* Wv = (const float*)d_in[5];
    const float* bv = (const float*)d_in[6];
    const float* Wo = (const float*)d_in[7];
    const float* bo = (const float*)d_in[8];
    float* out = (float*)d_out;

    dim3 grid(2048), block(256);
    hipLaunchKernelGGL(swin_attn_kernel, grid, block, 0, stream,
                       x, Wq, bq, Wk, bk, Wv, bv, Wo, bo, out);
}

// Round 7
// 66.115 us; speedup vs baseline: 1.0305x; 1.0305x over previous
//
#include <hip/hip_runtime.h>
#include <hip/hip_bf16.h>
#include <stdint.h>

typedef float f32x4 __attribute__((ext_vector_type(4)));
typedef short s16x8 __attribute__((ext_vector_type(8)));
typedef unsigned short u16;
typedef u16 u16x4 __attribute__((ext_vector_type(4)));

__device__ __forceinline__ u16 f2bf(float f) {
    union { __hip_bfloat16 h; u16 u; } cv;
    cv.h = __float2bfloat16(f);
    return cv.u;
}
__device__ __forceinline__ int pkbf(float lo, float hi) {
    return (int)(unsigned)f2bf(lo) | ((int)(unsigned)f2bf(hi) << 16);
}
__device__ __forceinline__ f32x4 mfma16(s16x8 a, s16x8 b, f32x4 c) {
    return __builtin_amdgcn_mfma_f32_16x16x32_bf16(a, b, c, 0, 0, 0);
}
__device__ __forceinline__ float exp2_hw(float x) {
    float r; asm("v_exp_f32 %0, %1" : "=v"(r) : "v"(x)); return r;
}
// lane ^= 16 within 32-lane halves (verified R4-R6)
__device__ __forceinline__ int swz16(int v) {
    return __builtin_amdgcn_ds_swizzle(v, 0x401F);
}
// value at lane^32 (verified R4-R6)
__device__ __forceinline__ int xor32i(int v, bool lo32) {
    auto r = __builtin_amdgcn_permlane32_swap(v, v, false, false);
    return lo32 ? r[1] : r[0];
}
// lanes>=32 receive (lane-32)'s value; lanes<32 keep own (verified R5/R6)
__device__ __forceinline__ int pl_lo_to_hi(int v) {
    auto r = __builtin_amdgcn_permlane32_swap(v, v, false, false);
    return r[0];
}
__device__ __forceinline__ s16x8 frag4(int d0, int d1, int d2, int d3) {
    union { int i[4]; s16x8 v; } u;
    u.i[0] = d0; u.i[1] = d1; u.i[2] = d2; u.i[3] = d3;
    return u.v;
}
// compiler-only ordering fence; HW DS pipe is in-order per wave (proven R5/R6)
#define C_FENCE() asm volatile("" ::: "memory")

// x: (4,512,512,32) f32. Window=4, shift=2, heads=4, d=8.
// 1 wave = 1 window (16 tokens), 4 independent waves/block, 4 windows/wave.
// All fragment reads UNCONDITIONAL: invalid lanes read permanently-zero LDS
// pads via a 1-instruction address select (no exec-mask divergence).
__global__ __launch_bounds__(256) void swin_attn_kernel(
    const float* __restrict__ x,
    const float* __restrict__ Wq, const float* __restrict__ bq,
    const float* __restrict__ Wk, const float* __restrict__ bk,
    const float* __restrict__ Wv, const float* __restrict__ bv,
    const float* __restrict__ Wo, const float* __restrict__ bo,
    float* __restrict__ out)
{
    const int lane  = threadIdx.x & 63;
    const int wave  = threadIdx.x >> 6;
    const int c16   = lane & 15;
    const int g     = lane >> 4;
    const bool lo32 = (lane < 32);

    // per-wave staging with zero pads. qk row (stride 88): q 0..31 | qz 32..39 |
    // k 40..71 | kz 72..79 | pad. vT: 32 data rows + zero row 32. pB: 16 + zero row 16.
    __shared__ __align__(16) u16 qk[4][16][88];  // 2816 B/wave
    __shared__ __align__(16) u16 vT[4][33][24];  // 1584 B/wave
    __shared__ __align__(16) u16 pB[4][17][24];  //  816 B/wave

    const float qscale = 0.35355339059327373f * 1.4426950408889634f; // 1/sqrt(8)*log2e

    // ---- zero-init pads (once; pads never written again) ----
    {
        const int col = (g < 2) ? (32 + 4 * g) : (72 + 4 * (g - 2));
        *(u16x4*)&qk[wave][c16][col] = (u16x4){0, 0, 0, 0};
        if (lane < 6) *(u16x4*)&vT[wave][32][lane * 4] = (u16x4){0, 0, 0, 0};
        if (lane < 6) *(u16x4*)&pB[wave][16][lane * 4] = (u16x4){0, 0, 0, 0};
    }
    C_FENCE();

    // ---- weights in registers (layouts proven R3/R5) ----
    s16x8 wqkv[6];
    #pragma unroll
    for (int j = 0; j < 6; ++j) {
        const float* Wsrc = (j < 2) ? Wq : (j < 4) ? Wk : Wv;
        const int colW = ((j & 1) << 4) | c16;
        const float sc = (j < 2) ? qscale : 1.0f;
        s16x8 wf;
        #pragma unroll
        for (int jj = 0; jj < 8; ++jj)
            wf[jj] = (short)f2bf(Wsrc[(g * 8 + jj) * 32 + colW] * sc);
        wqkv[j] = wf;
    }
    f32x4 bias_qk[4];
    #pragma unroll
    for (int j = 0; j < 4; ++j) {
        const float* bsrc = (j < 2) ? bq : bk;
        const float sc = (j < 2) ? qscale : 1.0f;
        #pragma unroll
        for (int i = 0; i < 4; ++i)
            bias_qk[j][i] = bsrc[((j & 1) << 4) + 4 * g + i] * sc;
    }
    f32x4 bias_v[2];
    #pragma unroll
    for (int jv = 0; jv < 2; ++jv) {
        float b = bv[jv * 16 + c16];
        bias_v[jv] = (f32x4){b, b, b, b};
    }
    s16x8 wo_frag[2];
    f32x4 bo_frag[2];
    #pragma unroll
    for (int j2 = 0; j2 < 2; ++j2) {
        const int cout = j2 * 16 + c16;
        s16x8 wf;
        #pragma unroll
        for (int jj = 0; jj < 8; ++jj) {
            const int h = (g >> 1) * 2 + (jj >> 2);
            const int d = 4 * (g & 1) + (jj & 3);
            wf[jj] = (short)f2bf(Wo[(h * 8 + d) * 32 + cout]);
        }
        wo_frag[j2] = wf;
        #pragma unroll
        for (int i = 0; i < 4; ++i)
            bo_frag[j2][i] = bo[j2 * 16 + 4 * g + i];
    }

    const f32x4 zero4 = {0.f, 0.f, 0.f, 0.f};

    // hoisted fragment pointers (address cndmask once, not per head)
    const u16* ap_base = (g == 0) ? &qk[wave][c16][40] : &qk[wave][c16][72]; // +h*8 if g==0
    const u16* bp_base = (g == 0) ? &qk[wave][c16][0]  : &qk[wave][c16][32];
    const int  hstep   = (g == 0) ? 8 : 0;
    const u16* pp      = (g < 2) ? &pB[wave][c16][g * 8] : &pB[wave][16][0];
    const u16* vp_base = (g < 2) ? &vT[wave][c16 & 7][g * 8] : &vT[wave][32][0];
    const int  vstep   = (g < 2) ? 8 * 24 : 0; // +h*8 rows if valid

    // prologue: load window 0's x
    const int wbase = (blockIdx.x * 4 + wave) * 4;
    long curpix;
    f32x4 px0, px1;
    {
        const int w = wbase;
        const int b = w >> 14, rem = w & 16383, wi = rem >> 7, wj = rem & 127;
        const int row  = (wi * 4 + (c16 >> 2) + 2) & 511;
        const int colp = (wj * 4 + (c16 & 3) + 2) & 511;
        curpix = ((((long)b << 9) + row) * 512 + colp) * 32;
        px0 = *(const f32x4*)(x + curpix + g * 8);
        px1 = *(const f32x4*)(x + curpix + g * 8 + 4);
    }

    #pragma unroll 1
    for (int it = 0; it < 4; ++it) {
        const long pixbase = curpix;
        s16x8 xfrag = frag4(pkbf(px0[0], px0[1]), pkbf(px0[2], px0[3]),
                            pkbf(px1[0], px1[1]), pkbf(px1[2], px1[3]));

        // ---- phase A: projections -> LDS staging ----
        #pragma unroll
        for (int j = 0; j < 4; ++j) {     // q,k: C^T = W^T X^T (token-major)
            f32x4 c = mfma16(wqkv[j], xfrag, bias_qk[j]);
            const int col = (j < 2) ? (j * 16 + 4 * g) : (40 + (j - 2) * 16 + 4 * g);
            u16x4 qv;
            #pragma unroll
            for (int i = 0; i < 4; ++i) qv[i] = f2bf(c[i]);
            *(u16x4*)&qk[wave][c16][col] = qv;
        }
        #pragma unroll
        for (int jv = 0; jv < 2; ++jv) {  // v: C = X Wv (vslot-major)
            f32x4 c = mfma16(xfrag, wqkv[4 + jv], bias_v[jv]);
            u16x4 vv;
            #pragma unroll
            for (int i = 0; i < 4; ++i) vv[i] = f2bf(c[i]);
            *(u16x4*)&vT[wave][jv * 16 + c16][4 * g] = vv;
        }

        // prefetch next window's x (wrap at it==3: harmless re-read)
        {
            const int w = wbase + ((it + 1) & 3);
            const int b = w >> 14, rem = w & 16383, wi = rem >> 7, wj = rem & 127;
            const int row  = (wi * 4 + (c16 >> 2) + 2) & 511;
            const int colp = (wj * 4 + (c16 & 3) + 2) & 511;
            const long np = ((((long)b << 9) + row) * 512 + colp) * 32;
            px0 = *(const f32x4*)(x + np + g * 8);
            px1 = *(const f32x4*)(x + np + g * 8 + 4);
            curpix = np;
        }
        f32x4 r0 = *(const f32x4*)(x + pixbase + 4 * g);
        f32x4 r1 = *(const f32x4*)(x + pixbase + 16 + 4 * g);

        C_FENCE(); // staging writes -> fragment reads (in-order DS pipe)

        // ---- phase B: per head, scores + softmax + LDS-P + PV ----
        f32x4 o_acc[4];
        #pragma unroll
        for (int h = 0; h < 4; ++h) {
            s16x8 afrag = *(const s16x8*)(ap_base + h * hstep); // K_h[kt=c16][d] / zeros
            s16x8 bfrag = *(const s16x8*)(bp_base + h * hstep); // Q_h[qt=c16][d] / zeros
            f32x4 s = mfma16(afrag, bfrag, zero4); // S^T rows kt=4g+i, col qt=c16

            float e0 = exp2_hw(s[0]), e1 = exp2_hw(s[1]);
            float e2 = exp2_hw(s[2]), e3 = exp2_hw(s[3]);
            float part = (e0 + e1) + (e2 + e3);
            float sum  = part + __int_as_float(swz16(__float_as_int(part)));
            sum += __int_as_float(xor32i(__float_as_int(sum), lo32));
            const float inv = __builtin_amdgcn_rcpf(sum);
            u16x4 pv;
            pv[0] = f2bf(e0 * inv); pv[1] = f2bf(e1 * inv);
            pv[2] = f2bf(e2 * inv); pv[3] = f2bf(e3 * inv);
            *(u16x4*)&pB[wave][c16][4 * g] = pv; // [qt][kt]
            C_FENCE(); // P write -> P read

            s16x8 vfrag = *(const s16x8*)(vp_base + h * vstep); // V rows / zeros
            s16x8 pfrag = *(const s16x8*)pp;                    // P / zeros
            o_acc[h] = mfma16(vfrag, pfrag, zero4); // O_h rows d=4g+i (g<2), col qt=c16
            C_FENCE(); // P read before next head's P write
        }

        // ---- phase C: ofrag from registers (proven R5/R6) ----
        int t00 = pkbf(o_acc[0][0], o_acc[0][1]), t01 = pkbf(o_acc[0][2], o_acc[0][3]);
        int t10 = pkbf(o_acc[1][0], o_acc[1][1]), t11 = pkbf(o_acc[1][2], o_acc[1][3]);
        int t20 = pkbf(o_acc[2][0], o_acc[2][1]), t21 = pkbf(o_acc[2][2], o_acc[2][3]);
        int t30 = pkbf(o_acc[3][0], o_acc[3][1]), t31 = pkbf(o_acc[3][2], o_acc[3][3]);
        int m20 = pl_lo_to_hi(t20), m21 = pl_lo_to_hi(t21);
        int m30 = pl_lo_to_hi(t30), m31 = pl_lo_to_hi(t31);
        s16x8 ofrag = frag4(lo32 ? t00 : m20, lo32 ? t01 : m21,
                            lo32 ? t10 : m30, lo32 ? t11 : m31);

        // ---- out-proj + bias + residual + store ----
        f32x4 ci0 = bo_frag[0], ci1 = bo_frag[1];
        #pragma unroll
        for (int i = 0; i < 4; ++i) { ci0[i] += r0[i]; ci1[i] += r1[i]; }
        f32x4 c0 = mfma16(wo_frag[0], ofrag, ci0); // rows cout 4g+i, col token c16
        f32x4 c1 = mfma16(wo_frag[1], ofrag, ci1);
        *(f32x4*)(out + pixbase + 4 * g) = c0;
        *(f32x4*)(out + pixbase + 16 + 4 * g) = c1;

        C_FENCE(); // next window's staging after this window's reads
    }
}

extern "C" void kernel_launch(void* const* d_in, const int* in_sizes, int n_in,
                              void* d_out, int out_size, void* d_ws, size_t ws_size,
                              hipStream_t stream) {
    const float* x  = (const float*)d_in[0];
    const float* Wq = (const float*)d_in[1];
    const float* bq = (const float*)d_in[2];
    const float* Wk = (const float*)d_in[3];
    const float* bk = (const float*)d_in[4];
    const float* Wv = (const float*)d_in[5];
    const float* bv = (const float*)d_in[6];
    const float* Wo = (const float*)d_in[7];
    const float* bo = (const float*)d_in[8];
    float* out = (float*)d_out;

    dim3 grid(4096), block(256);
    hipLaunchKernelGGL(swin_attn_kernel, grid, block, 0, stream,
                       x, Wq, bq, Wk, bk, Wv, bv, Wo, bo, out);
}

// Round 8
// 65.266 us; speedup vs baseline: 1.0439x; 1.0130x over previous
//
#include <hip/hip_runtime.h>
#include <hip/hip_bf16.h>
#include <stdint.h>

typedef float f32x4 __attribute__((ext_vector_type(4)));
typedef short s16x8 __attribute__((ext_vector_type(8)));
typedef unsigned short u16;
typedef u16 u16x4 __attribute__((ext_vector_type(4)));

__device__ __align__(16) float g_tbl[16 * 256]; // 16 units x 64 lanes x f32x4 (16 KB)

__device__ __forceinline__ u16 f2bf(float f) {
    union { __hip_bfloat16 h; u16 u; } cv;
    cv.h = __float2bfloat16(f);
    return cv.u;
}
__device__ __forceinline__ int pkbf(float lo, float hi) {
    return (int)(unsigned)f2bf(lo) | ((int)(unsigned)f2bf(hi) << 16);
}
__device__ __forceinline__ f32x4 mfma16(s16x8 a, s16x8 b, f32x4 c) {
    return __builtin_amdgcn_mfma_f32_16x16x32_bf16(a, b, c, 0, 0, 0);
}
__device__ __forceinline__ float exp2_hw(float x) {
    float r; asm("v_exp_f32 %0, %1" : "=v"(r) : "v"(x)); return r;
}
// lane ^= 16 within 32-lane halves (verified R4-R7)
__device__ __forceinline__ int swz16(int v) {
    return __builtin_amdgcn_ds_swizzle(v, 0x401F);
}
// value at lane^32 (verified R4-R7)
__device__ __forceinline__ int xor32i(int v, bool lo32) {
    auto r = __builtin_amdgcn_permlane32_swap(v, v, false, false);
    return lo32 ? r[1] : r[0];
}
// lanes>=32 receive (lane-32)'s value; lanes<32 keep own (verified R5-R7)
__device__ __forceinline__ int pl_lo_to_hi(int v) {
    auto r = __builtin_amdgcn_permlane32_swap(v, v, false, false);
    return r[0];
}
__device__ __forceinline__ s16x8 frag4(int d0, int d1, int d2, int d3) {
    union { int i[4]; s16x8 v; } u;
    u.i[0] = d0; u.i[1] = d1; u.i[2] = d2; u.i[3] = d3;
    return u.v;
}
// compiler-only ordering fence; HW DS pipe is in-order per wave (proven R5-R7)
#define C_FENCE() asm volatile("" ::: "memory")

// ---- one-block setup: precompute per-lane fragment table (R7 prologue math) ----
__global__ void setup_kernel(
    const float* __restrict__ Wq, const float* __restrict__ bq,
    const float* __restrict__ Wk, const float* __restrict__ bk,
    const float* __restrict__ Wv, const float* __restrict__ bv,
    const float* __restrict__ Wo, const float* __restrict__ bo)
{
    const int lane = threadIdx.x & 63;
    if (threadIdx.x >= 64) return;
    const int c16 = lane & 15;
    const int g   = lane >> 4;
    const float qscale = 0.35355339059327373f * 1.4426950408889634f; // 1/sqrt(8)*log2e

    f32x4* T = (f32x4*)g_tbl;
    union { s16x8 s; f32x4 f; } cv;

    // units 0-5: wqkv fragments
    #pragma unroll
    for (int j = 0; j < 6; ++j) {
        const float* Wsrc = (j < 2) ? Wq : (j < 4) ? Wk : Wv;
        const int colW = ((j & 1) << 4) | c16;
        const float sc = (j < 2) ? qscale : 1.0f;
        s16x8 wf;
        #pragma unroll
        for (int jj = 0; jj < 8; ++jj)
            wf[jj] = (short)f2bf(Wsrc[(g * 8 + jj) * 32 + colW] * sc);
        cv.s = wf;
        T[j * 64 + lane] = cv.f;
    }
    // units 6-7: wo fragments (k-slot (g,jj) -> h=(g>>1)*2+(jj>>2), d=4*(g&1)+(jj&3))
    #pragma unroll
    for (int j2 = 0; j2 < 2; ++j2) {
        const int cout = j2 * 16 + c16;
        s16x8 wf;
        #pragma unroll
        for (int jj = 0; jj < 8; ++jj) {
            const int h = (g >> 1) * 2 + (jj >> 2);
            const int d = 4 * (g & 1) + (jj & 3);
            wf[jj] = (short)f2bf(Wo[(h * 8 + d) * 32 + cout]);
        }
        cv.s = wf;
        T[(6 + j2) * 64 + lane] = cv.f;
    }
    // units 8-11: bias_qk
    #pragma unroll
    for (int j = 0; j < 4; ++j) {
        const float* bsrc = (j < 2) ? bq : bk;
        const float sc = (j < 2) ? qscale : 1.0f;
        f32x4 b;
        #pragma unroll
        for (int i = 0; i < 4; ++i)
            b[i] = bsrc[((j & 1) << 4) + 4 * g + i] * sc;
        T[(8 + j) * 64 + lane] = b;
    }
    // units 12-13: bias_v
    #pragma unroll
    for (int jv = 0; jv < 2; ++jv) {
        float b = bv[jv * 16 + c16];
        T[(12 + jv) * 64 + lane] = (f32x4){b, b, b, b};
    }
    // units 14-15: bo
    #pragma unroll
    for (int j2 = 0; j2 < 2; ++j2) {
        f32x4 b;
        #pragma unroll
        for (int i = 0; i < 4; ++i)
            b[i] = bo[j2 * 16 + 4 * g + i];
        T[(14 + j2) * 64 + lane] = b;
    }
}

// x: (4,512,512,32) f32. Window=4, shift=2, heads=4, d=8.
// 1 wave = 1 window (16 tokens), 4 independent waves/block, 4 windows/wave.
// Prologue = 16 coalesced dwordx4 loads from the precomputed fragment table.
__global__ __launch_bounds__(256) void swin_attn_kernel(
    const float* __restrict__ x, float* __restrict__ out)
{
    const int lane  = threadIdx.x & 63;
    const int wave  = threadIdx.x >> 6;
    const int c16   = lane & 15;
    const int g     = lane >> 4;
    const bool lo32 = (lane < 32);

    // per-wave staging with zero pads (R7 layout, proven)
    __shared__ __align__(16) u16 qk[4][16][88];  // q 0..31 | qz | k 40..71 | kz
    __shared__ __align__(16) u16 vT[4][33][24];
    __shared__ __align__(16) u16 pB[4][17][24];

    // ---- zero-init pads (once) ----
    {
        const int col = (g < 2) ? (32 + 4 * g) : (72 + 4 * (g - 2));
        *(u16x4*)&qk[wave][c16][col] = (u16x4){0, 0, 0, 0};
        if (lane < 6) *(u16x4*)&vT[wave][32][lane * 4] = (u16x4){0, 0, 0, 0};
        if (lane < 6) *(u16x4*)&pB[wave][16][lane * 4] = (u16x4){0, 0, 0, 0};
    }
    C_FENCE();

    // ---- prologue: 16 coalesced loads from fragment table ----
    const f32x4* T = (const f32x4*)g_tbl;
    f32x4 u[16];
    #pragma unroll
    for (int k = 0; k < 16; ++k) u[k] = T[k * 64 + lane];
    union { f32x4 f; s16x8 s; } cv;
    s16x8 wqkv[6], wo_frag[2];
    #pragma unroll
    for (int j = 0; j < 6; ++j) { cv.f = u[j]; wqkv[j] = cv.s; }
    cv.f = u[6]; wo_frag[0] = cv.s;
    cv.f = u[7]; wo_frag[1] = cv.s;
    f32x4 bias_qk[4] = {u[8], u[9], u[10], u[11]};
    f32x4 bias_v[2]  = {u[12], u[13]};
    f32x4 bo_frag[2] = {u[14], u[15]};

    const f32x4 zero4 = {0.f, 0.f, 0.f, 0.f};

    // hoisted fragment pointers (R7, proven)
    const u16* ap_base = (g == 0) ? &qk[wave][c16][40] : &qk[wave][c16][72];
    const u16* bp_base = (g == 0) ? &qk[wave][c16][0]  : &qk[wave][c16][32];
    const int  hstep   = (g == 0) ? 8 : 0;
    const u16* pp      = (g < 2) ? &pB[wave][c16][g * 8] : &pB[wave][16][0];
    const u16* vp_base = (g < 2) ? &vT[wave][c16 & 7][g * 8] : &vT[wave][32][0];
    const int  vstep   = (g < 2) ? 8 * 24 : 0;

    // prologue: load window 0's x
    const int wbase = (blockIdx.x * 4 + wave) * 4;
    long curpix;
    f32x4 px0, px1;
    {
        const int w = wbase;
        const int b = w >> 14, rem = w & 16383, wi = rem >> 7, wj = rem & 127;
        const int row  = (wi * 4 + (c16 >> 2) + 2) & 511;
        const int colp = (wj * 4 + (c16 & 3) + 2) & 511;
        curpix = ((((long)b << 9) + row) * 512 + colp) * 32;
        px0 = *(const f32x4*)(x + curpix + g * 8);
        px1 = *(const f32x4*)(x + curpix + g * 8 + 4);
    }

    #pragma unroll 1
    for (int it = 0; it < 4; ++it) {
        const long pixbase = curpix;
        s16x8 xfrag = frag4(pkbf(px0[0], px0[1]), pkbf(px0[2], px0[3]),
                            pkbf(px1[0], px1[1]), pkbf(px1[2], px1[3]));

        // ---- phase A: projections -> LDS staging ----
        #pragma unroll
        for (int j = 0; j < 4; ++j) {     // q,k: C^T = W^T X^T (token-major)
            f32x4 c = mfma16(wqkv[j], xfrag, bias_qk[j]);
            const int col = (j < 2) ? (j * 16 + 4 * g) : (40 + (j - 2) * 16 + 4 * g);
            u16x4 qv;
            #pragma unroll
            for (int i = 0; i < 4; ++i) qv[i] = f2bf(c[i]);
            *(u16x4*)&qk[wave][c16][col] = qv;
        }
        #pragma unroll
        for (int jv = 0; jv < 2; ++jv) {  // v: C = X Wv (vslot-major)
            f32x4 c = mfma16(xfrag, wqkv[4 + jv], bias_v[jv]);
            u16x4 vv;
            #pragma unroll
            for (int i = 0; i < 4; ++i) vv[i] = f2bf(c[i]);
            *(u16x4*)&vT[wave][jv * 16 + c16][4 * g] = vv;
        }

        // prefetch next window's x (wrap at it==3: harmless re-read)
        {
            const int w = wbase + ((it + 1) & 3);
            const int b = w >> 14, rem = w & 16383, wi = rem >> 7, wj = rem & 127;
            const int row  = (wi * 4 + (c16 >> 2) + 2) & 511;
            const int colp = (wj * 4 + (c16 & 3) + 2) & 511;
            const long np = ((((long)b << 9) + row) * 512 + colp) * 32;
            px0 = *(const f32x4*)(x + np + g * 8);
            px1 = *(const f32x4*)(x + np + g * 8 + 4);
            curpix = np;
        }
        f32x4 r0 = *(const f32x4*)(x + pixbase + 4 * g);
        f32x4 r1 = *(const f32x4*)(x + pixbase + 16 + 4 * g);

        C_FENCE(); // staging writes -> fragment reads (in-order DS pipe)

        // ---- phase B: per head, scores + softmax + LDS-P + PV ----
        f32x4 o_acc[4];
        #pragma unroll
        for (int h = 0; h < 4; ++h) {
            s16x8 afrag = *(const s16x8*)(ap_base + h * hstep); // K_h[kt=c16][d] / zeros
            s16x8 bfrag = *(const s16x8*)(bp_base + h * hstep); // Q_h[qt=c16][d] / zeros
            f32x4 s = mfma16(afrag, bfrag, zero4); // S^T rows kt=4g+i, col qt=c16

            float e0 = exp2_hw(s[0]), e1 = exp2_hw(s[1]);
            float e2 = exp2_hw(s[2]), e3 = exp2_hw(s[3]);
            float part = (e0 + e1) + (e2 + e3);
            float sum  = part + __int_as_float(swz16(__float_as_int(part)));
            sum += __int_as_float(xor32i(__float_as_int(sum), lo32));
            const float inv = __builtin_amdgcn_rcpf(sum);
            u16x4 pv;
            pv[0] = f2bf(e0 * inv); pv[1] = f2bf(e1 * inv);
            pv[2] = f2bf(e2 * inv); pv[3] = f2bf(e3 * inv);
            *(u16x4*)&pB[wave][c16][4 * g] = pv; // [qt][kt]
            C_FENCE(); // P write -> P read

            s16x8 vfrag = *(const s16x8*)(vp_base + h * vstep); // V rows / zeros
            s16x8 pfrag = *(const s16x8*)pp;                    // P / zeros
            o_acc[h] = mfma16(vfrag, pfrag, zero4); // O_h rows d=4g+i (g<2), col qt=c16
            C_FENCE(); // P read before next head's P write
        }

        // ---- phase C: ofrag from registers (proven R5-R7) ----
        int t00 = pkbf(o_acc[0][0], o_acc[0][1]), t01 = pkbf(o_acc[0][2], o_acc[0][3]);
        int t10 = pkbf(o_acc[1][0], o_acc[1][1]), t11 = pkbf(o_acc[1][2], o_acc[1][3]);
        int t20 = pkbf(o_acc[2][0], o_acc[2][1]), t21 = pkbf(o_acc[2][2], o_acc[2][3]);
        int t30 = pkbf(o_acc[3][0], o_acc[3][1]), t31 = pkbf(o_acc[3][2], o_acc[3][3]);
        int m20 = pl_lo_to_hi(t20), m21 = pl_lo_to_hi(t21);
        int m30 = pl_lo_to_hi(t30), m31 = pl_lo_to_hi(t31);
        s16x8 ofrag = frag4(lo32 ? t00 : m20, lo32 ? t01 : m21,
                            lo32 ? t10 : m30, lo32 ? t11 : m31);

        // ---- out-proj + bias + residual + store ----
        f32x4 ci0 = bo_frag[0], ci1 = bo_frag[1];
        #pragma unroll
        for (int i = 0; i < 4; ++i) { ci0[i] += r0[i]; ci1[i] += r1[i]; }
        f32x4 c0 = mfma16(wo_frag[0], ofrag, ci0); // rows cout 4g+i, col token c16
        f32x4 c1 = mfma16(wo_frag[1], ofrag, ci1);
        *(f32x4*)(out + pixbase + 4 * g) = c0;
        *(f32x4*)(out + pixbase + 16 + 4 * g) = c1;

        C_FENCE(); // next window's staging after this window's reads
    }
}

extern "C" void kernel_launch(void* const* d_in, const int* in_sizes, int n_in,
                              void* d_out, int out_size, void* d_ws, size_t ws_size,
                              hipStream_t stream) {
    const float* x  = (const float*)d_in[0];
    const float* Wq = (const float*)d_in[1];
    const float* bq = (const float*)d_in[2];
    const float* Wk = (const float*)d_in[3];
    const float* bk = (const float*)d_in[4];
    const float* Wv = (const float*)d_in[5];
    const float* bv = (const float*)d_in[6];
    const float* Wo = (const float*)d_in[7];
    const float* bo = (const float*)d_in[8];
    float* out = (float*)d_out;

    hipLaunchKernelGGL(setup_kernel, dim3(1), dim3(64), 0, stream,
                       Wq, bq, Wk, bk, Wv, bv, Wo, bo);
    hipLaunchKernelGGL(swin_attn_kernel, dim3(4096), dim3(256), 0, stream,
                       x, out);
}